// Round 5
// baseline (220.826 us; speedup 1.0000x reference)
//
#include <hip/hip_runtime.h>

#define NN 8192
#define WW_ 128
#define EPSF 1e-8f

typedef float vfloat4 __attribute__((ext_vector_type(4)));

// ws float offsets
#define S_LOGITS 0
#define S_ALLOC  8192
#define S_WW     16384
#define S_RET    24576
#define S_G      32768
#define S_RANK   40960
#define S_RC     49152      // 8192*4
#define S_FWD    81920      // 8192*4 (fallback)
#define S_BWD    114688     // 8192*4 (fallback)
#define S_SCAL   147456     // 32 scalars: [6]=sum exp(logit), [8]=sum alloc
#define S_BWDP   262144     // 8*32768 = 262144 floats (1 MB)
#define S_FWDP   524288     // 64*32768 = 2097152 floats (8 MB)

// output float offsets
#define O_RV 0
#define O_NM 512
#define O_NU 1049088
#define O_NP 1057280
#define O_NL 1065472
#define O_NR 68174336

// scratch carved out of the (not-yet-written) new_link output region
#define P_APART 0           // 16*8192
#define P_CPART 131072      // 16*8192
#define P_RVP   262144      // 256*512 rv partials

// ---- per-row: content logits, retention, read_vectors partials (no atomics) ----
__global__ __launch_bounds__(256, 4) void k_rowstats(
    const float* __restrict__ mem, const float* __restrict__ rw,
    const float* __restrict__ wk, const float* __restrict__ fg,
    const float* __restrict__ wstr,
    float* __restrict__ rvp, float* __restrict__ logits, float* __restrict__ ret,
    float* __restrict__ scal)
{
    __shared__ float sb[4][512];
    int lane = threadIdx.x & 63;
    int w = threadIdx.x >> 6;
    int wave = (blockIdx.x << 2) + w;            // 0..1023
    int c = lane * 2;
    float2 wk2 = *(const float2*)&wk[c];
    float4 fg4 = *(const float4*)&fg[0];
    float ws = wstr[0];
    float nw = wk2.x * wk2.x + wk2.y * wk2.y;
    #pragma unroll
    for (int s = 1; s < 64; s <<= 1) nw += __shfl_xor(nw, s);
    float wkn = sqrtf(nw);

    float arv[2][4];
    #pragma unroll
    for (int a = 0; a < 2; a++)
        #pragma unroll
        for (int r = 0; r < 4; r++) arv[a][r] = 0.f;
    float se = 0.f;
    int i0 = wave * 8;
    for (int t = 0; t < 8; t++) {
        int i = i0 + t;
        float2 m2 = *(const float2*)&mem[i * WW_ + c];
        float4 rwi = *(const float4*)&rw[i * 4];
        float dp = m2.x * wk2.x + m2.y * wk2.y;
        float nq = m2.x * m2.x + m2.y * m2.y;
        #pragma unroll
        for (int s = 1; s < 64; s <<= 1) { dp += __shfl_xor(dp, s); nq += __shfl_xor(nq, s); }
        arv[0][0] += m2.x * rwi.x; arv[0][1] += m2.x * rwi.y; arv[0][2] += m2.x * rwi.z; arv[0][3] += m2.x * rwi.w;
        arv[1][0] += m2.y * rwi.x; arv[1][1] += m2.y * rwi.y; arv[1][2] += m2.y * rwi.z; arv[1][3] += m2.y * rwi.w;
        if (lane == 0) {
            float denom = fmaxf(sqrtf(nq) * wkn, EPSF);
            float lg = dp / denom * ws;
            logits[i] = lg;
            ret[i] = (1.f - rwi.x * fg4.x) * (1.f - rwi.y * fg4.y) *
                     (1.f - rwi.z * fg4.z) * (1.f - rwi.w * fg4.w);
            se += __expf(lg);
        }
    }
    if (lane == 0) atomicAdd(&scal[6], se);
    #pragma unroll
    for (int a = 0; a < 2; a++)
        #pragma unroll
        for (int r = 0; r < 4; r++)
            sb[w][(c + a) * 4 + r] = arv[a][r];
    __syncthreads();
    for (int idx = threadIdx.x; idx < 512; idx += 256)
        rvp[blockIdx.x * 512 + idx] = sb[0][idx] + sb[1][idx] + sb[2][idx] + sb[3][idx];
}

// ---- allocation partials (masked products + rank counts); also zeroes fwd/bwd (fallback) ----
__global__ __launch_bounds__(256) void k_apart(const float* __restrict__ u,
                                               float* __restrict__ apart,
                                               float* __restrict__ cpart,
                                               float* __restrict__ fbzero) {
    __shared__ float su[512];
    int gtid = blockIdx.x * 256 + threadIdx.x;
    if (gtid < 65536) fbzero[gtid] = 0.f;
    int jc = blockIdx.x >> 5;
    int ib = blockIdx.x & 31;
    int t = threadIdx.x;
    for (int q = t; q < 512; q += 256) su[q] = u[jc * 512 + q];
    __syncthreads();
    int i = ib * 256 + t;
    float ui = u[i];
    float p0 = 1.f, p1 = 1.f, p2 = 1.f, p3 = 1.f;
    int c0 = 0, c1 = 0, c2 = 0, c3 = 0;
    int jbase = jc * 512;
    for (int q = 0; q < 512; q += 4) {
        float a0 = su[q], a1 = su[q + 1], a2 = su[q + 2], a3 = su[q + 3];
        int j0 = jbase + q;
        bool m0 = (a0 < ui) || (a0 == ui && j0     < i);
        bool m1 = (a1 < ui) || (a1 == ui && j0 + 1 < i);
        bool m2 = (a2 < ui) || (a2 == ui && j0 + 2 < i);
        bool m3 = (a3 < ui) || (a3 == ui && j0 + 3 < i);
        p0 *= m0 ? a0 : 1.f; c0 += m0;
        p1 *= m1 ? a1 : 1.f; c1 += m1;
        p2 *= m2 ? a2 : 1.f; c2 += m2;
        p3 *= m3 ? a3 : 1.f; c3 += m3;
    }
    apart[jc * NN + i] = (p0 * p1) * (p2 * p3);
    cpart[jc * NN + i] = (float)((c0 + c1) + (c2 + c3));
}

// ---- combine partials -> g[i], rank[i], sum(g); blocks 0,1 also reduce rv ----
__global__ __launch_bounds__(256) void k_grank(
    const float* __restrict__ u, const float* __restrict__ apart,
    const float* __restrict__ cpart, const float* __restrict__ rvp,
    float* __restrict__ g, int* __restrict__ rank,
    float* __restrict__ scal, float* __restrict__ rv_out) {
    __shared__ float sb[256];
    int i = blockIdx.x * 256 + threadIdx.x;
    float p = 1.f, c = 0.f;
    #pragma unroll
    for (int jc = 0; jc < 16; jc++) { p *= apart[jc * NN + i]; c += cpart[jc * NN + i]; }
    float gi = (1.f - u[i]) * p;
    g[i] = gi;
    rank[i] = (int)c;
    sb[threadIdx.x] = gi; __syncthreads();
    for (int s = 128; s > 0; s >>= 1) { if (threadIdx.x < s) sb[threadIdx.x] += sb[threadIdx.x + s]; __syncthreads(); }
    if (threadIdx.x == 0) atomicAdd(&scal[8], sb[0]);
    if (blockIdx.x < 2) {
        int idx = blockIdx.x * 256 + threadIdx.x;
        float acc = 0.f;
        for (int pb = 0; pb < 256; pb++) acc += rvp[pb * 512 + idx];
        rv_out[idx] = acc;
    }
}

// ---- reference's alloc_sorted[order] gather == out[rank[rank[m]]] = g[m] ----
__global__ void k_scatter(const float* __restrict__ g, const int* __restrict__ rank,
                          float* __restrict__ alloc) {
    int m = blockIdx.x * 256 + threadIdx.x;
    alloc[rank[rank[m]]] = g[m];
}

// ---- per-row epilogue: ww (inline), new_memory, usage, precedence, read_content ----
__global__ __launch_bounds__(256, 4) void k_rownew(
    const float* __restrict__ mem, const float* __restrict__ logits,
    const float* __restrict__ alloc, const float* __restrict__ u,
    const float* __restrict__ ret, const float* __restrict__ prec,
    const float* __restrict__ er, const float* __restrict__ wv,
    const float* __restrict__ rk, const float* __restrict__ rstr,
    const float* __restrict__ ag, const float* __restrict__ wg_,
    const float* __restrict__ scal,
    float* __restrict__ ww_out, float* __restrict__ nm_out,
    float* __restrict__ nu_out, float* __restrict__ np_out, float* __restrict__ rc_out)
{
    int lane = threadIdx.x & 63;
    int wave = (blockIdx.x << 2) + (threadIdx.x >> 6);
    int c = lane * 2;
    float2 er2 = *(const float2*)&er[c];
    float2 wv2 = *(const float2*)&wv[c];
    float4 rka = *(const float4*)&rk[c * 4];
    float4 rkb = *(const float4*)&rk[(c + 1) * 4];
    float4 rs4 = *(const float4*)&rstr[0];
    float n0 = rka.x * rka.x + rkb.x * rkb.x;
    float n1 = rka.y * rka.y + rkb.y * rkb.y;
    float n2 = rka.z * rka.z + rkb.z * rkb.z;
    float n3 = rka.w * rka.w + rkb.w * rkb.w;
    #pragma unroll
    for (int s = 1; s < 64; s <<= 1) {
        n0 += __shfl_xor(n0, s); n1 += __shfl_xor(n1, s);
        n2 += __shfl_xor(n2, s); n3 += __shfl_xor(n3, s);
    }
    float rkn0 = sqrtf(n0), rkn1 = sqrtf(n1), rkn2 = sqrtf(n2), rkn3 = sqrtf(n3);
    float invS = 1.f / scal[6];
    float Sg = scal[8];
    float ga = ag[0], wg = wg_[0];
    float wsum = wg * (ga * Sg + (1.f - ga));
    int i0 = wave * 4;
    for (int t = 0; t < 4; t++) {
        int i = i0 + t;
        float wwi = wg * (ga * alloc[i] + (1.f - ga) * __expf(logits[i]) * invS);
        float2 m2 = *(const float2*)&mem[i * WW_ + c];
        float nx = m2.x * (1.f - wwi * er2.x) + wwi * wv2.x;
        float ny = m2.y * (1.f - wwi * er2.y) + wwi * wv2.y;
        float2 nm2; nm2.x = nx; nm2.y = ny;
        *(float2*)&nm_out[i * WW_ + c] = nm2;
        float nq = nx * nx + ny * ny;
        float d0 = nx * rka.x + ny * rkb.x;
        float d1 = nx * rka.y + ny * rkb.y;
        float d2 = nx * rka.z + ny * rkb.z;
        float d3 = nx * rka.w + ny * rkb.w;
        #pragma unroll
        for (int s = 1; s < 64; s <<= 1) {
            nq += __shfl_xor(nq, s);
            d0 += __shfl_xor(d0, s); d1 += __shfl_xor(d1, s);
            d2 += __shfl_xor(d2, s); d3 += __shfl_xor(d3, s);
        }
        if (lane == 0) {
            float nrm = sqrtf(nq);
            float l0 = d0 / (nrm * rkn0) * rs4.x;
            float l1 = d1 / (nrm * rkn1) * rs4.y;
            float l2 = d2 / (nrm * rkn2) * rs4.z;
            float l3 = d3 / (nrm * rkn3) * rs4.w;
            float m4 = fmaxf(fmaxf(l0, l1), fmaxf(l2, l3));
            float e0 = __expf(l0 - m4), e1 = __expf(l1 - m4);
            float e2 = __expf(l2 - m4), e3 = __expf(l3 - m4);
            float si = 1.f / (e0 + e1 + e2 + e3);
            float4 rc; rc.x = e0 * si; rc.y = e1 * si; rc.z = e2 * si; rc.w = e3 * si;
            *(float4*)&rc_out[i * 4] = rc;
            ww_out[i] = wwi;
            float ui = u[i];
            nu_out[i] = (ui + wwi - ui * wwi) * ret[i];
            np_out[i] = (1.f - wsum) * prec[i] + wwi;
        }
    }
}

// ==== NEW k_link: column-stationary lanes, row-streaming, 2-deep pipeline ====
// grid (8, 64): block = 1024 cols x 128 rows, 4 waves each own 256 cols.
__global__ __launch_bounds__(256, 3) void k_link2(
    const float* __restrict__ link, const float* __restrict__ ww,
    const float* __restrict__ prec, const float* __restrict__ rw,
    float* __restrict__ nl_out, float* __restrict__ fwdp, float* __restrict__ bwdp)
{
    __shared__ float part[128][4][4];     // [row][wave][r]
    const int lane = threadIdx.x & 63;
    const int w = threadIdx.x >> 6;
    const int xb = blockIdx.x;            // 0..7
    const int yb = blockIdx.y;            // 0..63
    const int colbase = xb * 1024 + w * 256 + lane * 4;
    const int row0 = yb * 128;

    // per-column constants (hoisted)
    const float4 wwj = *(const float4*)&ww[colbase];
    const float4 pj  = *(const float4*)&prec[colbase];
    const float4 rj0 = *(const float4*)&rw[(colbase + 0) * 4];
    const float4 rj1 = *(const float4*)&rw[(colbase + 1) * 4];
    const float4 rj2 = *(const float4*)&rw[(colbase + 2) * 4];
    const float4 rj3 = *(const float4*)&rw[(colbase + 3) * 4];
    float4 rwT0, rwT1, rwT2, rwT3;        // rwT[r][c] = rw[col_c][r]
    rwT0.x = rj0.x; rwT0.y = rj1.x; rwT0.z = rj2.x; rwT0.w = rj3.x;
    rwT1.x = rj0.y; rwT1.y = rj1.y; rwT1.z = rj2.y; rwT1.w = rj3.y;
    rwT2.x = rj0.z; rwT2.y = rj1.z; rwT2.z = rj2.z; rwT2.w = rj3.z;
    rwT3.x = rj0.w; rwT3.y = rj1.w; rwT3.z = rj2.w; rwT3.w = rj3.w;

    float4 acc0, acc1, acc2, acc3;        // fwd acc[c] over r
    acc0.x = acc0.y = acc0.z = acc0.w = 0.f;
    acc1 = acc0; acc2 = acc0; acc3 = acc0;

    size_t off = (size_t)row0 * NN + colbase;
    // 2-deep software pipeline
    float4 La = *(const float4*)&link[off];
    float4 Lb = *(const float4*)&link[off + NN];
    float wwa = ww[row0], wwb = ww[row0 + 1];
    float4 rwa = *(const float4*)&rw[row0 * 4];
    float4 rwb = *(const float4*)&rw[(row0 + 1) * 4];

    #pragma unroll 2
    for (int t = 0; t < 128; ++t) {
        const float4 Lcur = La; La = Lb;
        const float wwi = wwa; wwa = wwb;
        const float4 rwi = rwa; rwa = rwb;
        if (t < 126) {
            const int i2 = row0 + t + 2;
            Lb  = *(const float4*)&link[off + 2 * (size_t)NN];
            wwb = ww[i2];
            rwb = *(const float4*)&rw[i2 * 4];
        }
        const float cc = 1.f - wwi;
        float4 e;
        e.x = (cc - wwj.x) * Lcur.x + wwi * pj.x;
        e.y = (cc - wwj.y) * Lcur.y + wwi * pj.y;
        e.z = (cc - wwj.z) * Lcur.z + wwi * pj.z;
        e.w = (cc - wwj.w) * Lcur.w + wwi * pj.w;
        vfloat4 ev; ev.x = e.x; ev.y = e.y; ev.z = e.z; ev.w = e.w;
        __builtin_nontemporal_store(ev, (vfloat4*)&nl_out[off]);
        off += NN;
        // fwd: acc[c] += e_c * rwi  (column-stationary, stays in regs)
        acc0.x += e.x * rwi.x; acc0.y += e.x * rwi.y; acc0.z += e.x * rwi.z; acc0.w += e.x * rwi.w;
        acc1.x += e.y * rwi.x; acc1.y += e.y * rwi.y; acc1.z += e.y * rwi.z; acc1.w += e.y * rwi.w;
        acc2.x += e.z * rwi.x; acc2.y += e.z * rwi.y; acc2.z += e.z * rwi.z; acc2.w += e.z * rwi.w;
        acc3.x += e.w * rwi.x; acc3.y += e.w * rwi.y; acc3.z += e.w * rwi.z; acc3.w += e.w * rwi.w;
        // bwd: b[r] = dot(e, rwT[r]); reduce 64 lanes via pair-merged butterfly
        float b0 = e.x * rwT0.x + e.y * rwT0.y + e.z * rwT0.z + e.w * rwT0.w;
        float b1 = e.x * rwT1.x + e.y * rwT1.y + e.z * rwT1.z + e.w * rwT1.w;
        float b2 = e.x * rwT2.x + e.y * rwT2.y + e.z * rwT2.z + e.w * rwT2.w;
        float b3 = e.x * rwT3.x + e.y * rwT3.y + e.z * rwT3.z + e.w * rwT3.w;
        float u01 = (lane & 1) ? b0 : b1;
        float v01 = __shfl_xor(u01, 1);
        float A = ((lane & 1) ? b1 : b0) + v01;
        float u23 = (lane & 1) ? b2 : b3;
        float v23 = __shfl_xor(u23, 1);
        float B = ((lane & 1) ? b3 : b2) + v23;
        float uu = (lane & 2) ? A : B;
        float vv = __shfl_xor(uu, 2);
        float S = ((lane & 2) ? B : A) + vv;
        #pragma unroll
        for (int s = 4; s < 64; s <<= 1) S += __shfl_xor(S, s);
        if (lane < 4) part[t][w][lane] = S;
    }
    __syncthreads();
    // bwd flush: 128 rows x 4 comps, no atomics (per-x partial)
    for (int q = threadIdx.x; q < 512; q += 256) {
        const int row = q >> 2, r = q & 3;
        const float s = part[row][0][r] + part[row][1][r] + part[row][2][r] + part[row][3][r];
        bwdp[xb * (NN * 4) + (row0 + row) * 4 + r] = s;
    }
    // fwd flush: per-y partial, contiguous 64B per lane
    float* fp = &fwdp[(size_t)yb * (NN * 4) + (size_t)colbase * 4];
    *(float4*)&fp[0]  = acc0;
    *(float4*)&fp[4]  = acc1;
    *(float4*)&fp[8]  = acc2;
    *(float4*)&fp[12] = acc3;
}

// ---- reduce partials + combine into new read weightings ----
__global__ __launch_bounds__(256) void k_final2(
    const float* __restrict__ fwdp, const float* __restrict__ bwdp,
    const float* __restrict__ rc, const float* __restrict__ modes,
    float* __restrict__ out) {
    int idx = blockIdx.x * 256 + threadIdx.x;   // < 32768
    int r = idx & 3;
    float f = 0.f;
    #pragma unroll 8
    for (int yv = 0; yv < 64; yv++) f += fwdp[yv * (NN * 4) + idx];
    float b = 0.f;
    #pragma unroll
    for (int xv = 0; xv < 8; xv++) b += bwdp[xv * (NN * 4) + idx];
    float m0 = modes[r * 3], m1 = modes[r * 3 + 1], m2 = modes[r * 3 + 2];
    out[idx] = b * m0 + rc[idx] * m1 + f * m2;
}

// ==== fallback (round-4) k_link + k_final, used if ws too small ====
__global__ __launch_bounds__(256, 4) void k_link(
    const float* __restrict__ link, const float* __restrict__ ww,
    const float* __restrict__ prec, const float* __restrict__ rw,
    float* __restrict__ nl_out, float* __restrict__ fwd, float* __restrict__ bwd)
{
    __shared__ float part[64][16][4];
    __shared__ float fl[4][256][4];
    const int lane = threadIdx.x & 63;
    const int w = threadIdx.x >> 6;
    const int j = blockIdx.x * 256 + lane * 4;
    const float4 wwj = *(const float4*)&ww[j];
    const float4 pj  = *(const float4*)&prec[j];
    const float4 rwj0 = *(const float4*)&rw[j * 4];
    const float4 rwj1 = *(const float4*)&rw[j * 4 + 4];
    const float4 rwj2 = *(const float4*)&rw[j * 4 + 8];
    const float4 rwj3 = *(const float4*)&rw[j * 4 + 12];
    float fa[4][4];
    #pragma unroll
    for (int a = 0; a < 4; a++)
        #pragma unroll
        for (int r = 0; r < 4; r++) fa[a][r] = 0.f;
    for (int sub = 0; sub < 4; ++sub) {
        const int i00 = blockIdx.y * 256 + sub * 64;
        const int irow0 = i00 + w * 16;
        #pragma unroll 4
        for (int t = 0; t < 16; ++t) {
            const int i = irow0 + t;
            const float wwi = ww[i];
            const float4 rwi = *(const float4*)&rw[i * 4];
            const size_t off = (size_t)i * NN + j;
            const float4 Lv = *(const float4*)&link[off];
            const float c0 = 1.f - wwi;
            float4 e;
            e.x = (c0 - wwj.x) * Lv.x + wwi * pj.x;
            e.y = (c0 - wwj.y) * Lv.y + wwi * pj.y;
            e.z = (c0 - wwj.z) * Lv.z + wwi * pj.z;
            e.w = (c0 - wwj.w) * Lv.w + wwi * pj.w;
            vfloat4 ev; ev.x = e.x; ev.y = e.y; ev.z = e.z; ev.w = e.w;
            __builtin_nontemporal_store(ev, (vfloat4*)&nl_out[off]);
            fa[0][0] += e.x * rwi.x; fa[0][1] += e.x * rwi.y; fa[0][2] += e.x * rwi.z; fa[0][3] += e.x * rwi.w;
            fa[1][0] += e.y * rwi.x; fa[1][1] += e.y * rwi.y; fa[1][2] += e.y * rwi.z; fa[1][3] += e.y * rwi.w;
            fa[2][0] += e.z * rwi.x; fa[2][1] += e.z * rwi.y; fa[2][2] += e.z * rwi.z; fa[2][3] += e.z * rwi.w;
            fa[3][0] += e.w * rwi.x; fa[3][1] += e.w * rwi.y; fa[3][2] += e.w * rwi.z; fa[3][3] += e.w * rwi.w;
            float b0 = e.x * rwj0.x + e.y * rwj1.x + e.z * rwj2.x + e.w * rwj3.x;
            float b1 = e.x * rwj0.y + e.y * rwj1.y + e.z * rwj2.y + e.w * rwj3.y;
            float b2 = e.x * rwj0.z + e.y * rwj1.z + e.z * rwj2.z + e.w * rwj3.z;
            float b3 = e.x * rwj0.w + e.y * rwj1.w + e.z * rwj2.w + e.w * rwj3.w;
            float u01 = (lane & 1) ? b0 : b1;
            float v01 = __shfl_xor(u01, 1);
            float A = ((lane & 1) ? b1 : b0) + v01;
            float u23 = (lane & 1) ? b2 : b3;
            float v23 = __shfl_xor(u23, 1);
            float B = ((lane & 1) ? b3 : b2) + v23;
            float uu = (lane & 2) ? A : B;
            float vv = __shfl_xor(uu, 2);
            float S = ((lane & 2) ? B : A) + vv;
            const int row = w * 16 + t;
            part[row][((lane >> 2) + row) & 15][lane & 3] = S;
        }
        __syncthreads();
        if (threadIdx.x < 64) {
            const int row = threadIdx.x;
            float4 acc; acc.x = 0.f; acc.y = 0.f; acc.z = 0.f; acc.w = 0.f;
            #pragma unroll
            for (int k = 0; k < 16; ++k) {
                const float4 p = *(const float4*)&part[row][(k + row) & 15][0];
                acc.x += p.x; acc.y += p.y; acc.z += p.z; acc.w += p.w;
            }
            const int i = i00 + row;
            atomicAdd(&bwd[i * 4 + 0], acc.x);
            atomicAdd(&bwd[i * 4 + 1], acc.y);
            atomicAdd(&bwd[i * 4 + 2], acc.z);
            atomicAdd(&bwd[i * 4 + 3], acc.w);
        }
        __syncthreads();
    }
    #pragma unroll
    for (int a = 0; a < 4; a++)
        #pragma unroll
        for (int r = 0; r < 4; r++)
            fl[w][lane * 4 + a][r] = fa[a][r];
    __syncthreads();
    const int col = threadIdx.x;
    const float4 s0 = *(const float4*)&fl[0][col][0];
    const float4 s1 = *(const float4*)&fl[1][col][0];
    const float4 s2 = *(const float4*)&fl[2][col][0];
    const float4 s3 = *(const float4*)&fl[3][col][0];
    atomicAdd(&fwd[(blockIdx.x * 256 + col) * 4 + 0], s0.x + s1.x + s2.x + s3.x);
    atomicAdd(&fwd[(blockIdx.x * 256 + col) * 4 + 1], s0.y + s1.y + s2.y + s3.y);
    atomicAdd(&fwd[(blockIdx.x * 256 + col) * 4 + 2], s0.z + s1.z + s2.z + s3.z);
    atomicAdd(&fwd[(blockIdx.x * 256 + col) * 4 + 3], s0.w + s1.w + s2.w + s3.w);
}

__global__ void k_final(const float* __restrict__ fwd, const float* __restrict__ bwd,
                        const float* __restrict__ rc, const float* __restrict__ modes,
                        float* __restrict__ out) {
    int idx = blockIdx.x * 256 + threadIdx.x;
    int r = idx & 3;
    float m0 = modes[r * 3], m1 = modes[r * 3 + 1], m2 = modes[r * 3 + 2];
    out[idx] = bwd[idx] * m0 + rc[idx] * m1 + fwd[idx] * m2;
}

extern "C" void kernel_launch(void* const* d_in, const int* in_sizes, int n_in,
                              void* d_out, int out_size, void* d_ws, size_t ws_size,
                              hipStream_t stream) {
    const float* mem   = (const float*)d_in[0];
    const float* u     = (const float*)d_in[1];
    const float* prec  = (const float*)d_in[2];
    const float* link  = (const float*)d_in[3];
    const float* rw    = (const float*)d_in[4];
    const float* rk    = (const float*)d_in[5];
    const float* rstr  = (const float*)d_in[6];
    const float* wk    = (const float*)d_in[7];
    const float* wstr  = (const float*)d_in[8];
    const float* er    = (const float*)d_in[9];
    const float* wv    = (const float*)d_in[10];
    const float* fg    = (const float*)d_in[11];
    const float* ag    = (const float*)d_in[12];
    const float* wg    = (const float*)d_in[13];
    const float* modes = (const float*)d_in[14];
    float* out = (float*)d_out;
    float* ws  = (float*)d_ws;
    float* nlr = out + O_NL;

    (void)hipMemsetAsync(ws + S_SCAL, 0, 32 * sizeof(float), stream);

    k_rowstats<<<256, 256, 0, stream>>>(mem, rw, wk, fg, wstr,
                                        nlr + P_RVP, ws + S_LOGITS, ws + S_RET, ws + S_SCAL);
    k_apart<<<512, 256, 0, stream>>>(u, nlr + P_APART, nlr + P_CPART, ws + S_FWD);
    k_grank<<<32, 256, 0, stream>>>(u, nlr + P_APART, nlr + P_CPART, nlr + P_RVP,
                                    ws + S_G, (int*)(ws + S_RANK), ws + S_SCAL, out + O_RV);
    k_scatter<<<32, 256, 0, stream>>>(ws + S_G, (const int*)(ws + S_RANK), ws + S_ALLOC);
    k_rownew<<<512, 256, 0, stream>>>(mem, ws + S_LOGITS, ws + S_ALLOC, u, ws + S_RET,
                                      prec, er, wv, rk, rstr, ag, wg, ws + S_SCAL,
                                      ws + S_WW, out + O_NM, out + O_NU, out + O_NP, ws + S_RC);

    const size_t need_bytes = (size_t)(S_FWDP + 64 * NN * 4) * sizeof(float);
    if (ws_size >= need_bytes) {
        dim3 lg(8, 64);
        k_link2<<<lg, 256, 0, stream>>>(link, ws + S_WW, prec, rw, out + O_NL,
                                        ws + S_FWDP, ws + S_BWDP);
        k_final2<<<128, 256, 0, stream>>>(ws + S_FWDP, ws + S_BWDP, ws + S_RC, modes, out + O_NR);
    } else {
        dim3 lg(32, 32);
        k_link<<<lg, 256, 0, stream>>>(link, ws + S_WW, prec, rw, out + O_NL,
                                       ws + S_FWD, ws + S_BWD);
        k_final<<<128, 256, 0, stream>>>(ws + S_FWD, ws + S_BWD, ws + S_RC, modes, out + O_NR);
    }
}

// Round 6
// 186.598 us; speedup vs baseline: 1.1834x; 1.1834x over previous
//
#include <hip/hip_runtime.h>

#define NN 8192
#define WW_ 128
#define EPSF 1e-8f

typedef float vfloat4 __attribute__((ext_vector_type(4)));

// ws float offsets
#define S_LOGITS 0
#define S_ALLOC  8192
#define S_WW     16384
#define S_RET    24576
#define S_G      32768
#define S_RANK   40960
#define S_RC     49152      // 8192*4
#define S_FWD    81920      // 8192*4 (fallback)
#define S_BWD    114688     // 8192*4 (fallback)
#define S_SCAL   147456     // 32 scalars: [6]=sum exp(logit), [8]=sum alloc
#define S_BWDP   262144     // 16 slots * 32768 = 524288 floats (2 MB)
#define S_FWDP   786432     // 64 slots * 32768 = 2097152 floats (8 MB)
#define WS_NEED_BYTES ((size_t)(S_FWDP + 64 * 32768) * 4)   // 11.53 MB

// output float offsets
#define O_RV 0
#define O_NM 512
#define O_NU 1049088
#define O_NP 1057280
#define O_NL 1065472
#define O_NR 68174336

// scratch carved out of the (not-yet-written) new_link output region
#define P_APART 0           // 16*8192
#define P_CPART 131072      // 16*8192
#define P_RVP   262144      // 256*512 rv partials

// ---- per-row: content logits, retention, read_vectors partials (no atomics) ----
__global__ __launch_bounds__(256, 4) void k_rowstats(
    const float* __restrict__ mem, const float* __restrict__ rw,
    const float* __restrict__ wk, const float* __restrict__ fg,
    const float* __restrict__ wstr,
    float* __restrict__ rvp, float* __restrict__ logits, float* __restrict__ ret,
    float* __restrict__ scal)
{
    __shared__ float sb[4][512];
    int lane = threadIdx.x & 63;
    int w = threadIdx.x >> 6;
    int wave = (blockIdx.x << 2) + w;            // 0..1023
    int c = lane * 2;
    float2 wk2 = *(const float2*)&wk[c];
    float4 fg4 = *(const float4*)&fg[0];
    float ws = wstr[0];
    float nw = wk2.x * wk2.x + wk2.y * wk2.y;
    #pragma unroll
    for (int s = 1; s < 64; s <<= 1) nw += __shfl_xor(nw, s);
    float wkn = sqrtf(nw);

    float arv[2][4];
    #pragma unroll
    for (int a = 0; a < 2; a++)
        #pragma unroll
        for (int r = 0; r < 4; r++) arv[a][r] = 0.f;
    float se = 0.f;
    int i0 = wave * 8;
    for (int t = 0; t < 8; t++) {
        int i = i0 + t;
        float2 m2 = *(const float2*)&mem[i * WW_ + c];
        float4 rwi = *(const float4*)&rw[i * 4];
        float dp = m2.x * wk2.x + m2.y * wk2.y;
        float nq = m2.x * m2.x + m2.y * m2.y;
        #pragma unroll
        for (int s = 1; s < 64; s <<= 1) { dp += __shfl_xor(dp, s); nq += __shfl_xor(nq, s); }
        arv[0][0] += m2.x * rwi.x; arv[0][1] += m2.x * rwi.y; arv[0][2] += m2.x * rwi.z; arv[0][3] += m2.x * rwi.w;
        arv[1][0] += m2.y * rwi.x; arv[1][1] += m2.y * rwi.y; arv[1][2] += m2.y * rwi.z; arv[1][3] += m2.y * rwi.w;
        if (lane == 0) {
            float denom = fmaxf(sqrtf(nq) * wkn, EPSF);
            float lg = dp / denom * ws;
            logits[i] = lg;
            ret[i] = (1.f - rwi.x * fg4.x) * (1.f - rwi.y * fg4.y) *
                     (1.f - rwi.z * fg4.z) * (1.f - rwi.w * fg4.w);
            se += __expf(lg);
        }
    }
    if (lane == 0) atomicAdd(&scal[6], se);
    #pragma unroll
    for (int a = 0; a < 2; a++)
        #pragma unroll
        for (int r = 0; r < 4; r++)
            sb[w][(c + a) * 4 + r] = arv[a][r];
    __syncthreads();
    for (int idx = threadIdx.x; idx < 512; idx += 256)
        rvp[blockIdx.x * 512 + idx] = sb[0][idx] + sb[1][idx] + sb[2][idx] + sb[3][idx];
}

// ---- allocation partials (masked products + rank counts); also zeroes fallback fwd/bwd ----
__global__ __launch_bounds__(256) void k_apart(const float* __restrict__ u,
                                               float* __restrict__ apart,
                                               float* __restrict__ cpart,
                                               float* __restrict__ fbzero) {
    __shared__ float su[512];
    int gtid = blockIdx.x * 256 + threadIdx.x;
    if (gtid < 65536) fbzero[gtid] = 0.f;
    int jc = blockIdx.x >> 5;
    int ib = blockIdx.x & 31;
    int t = threadIdx.x;
    for (int q = t; q < 512; q += 256) su[q] = u[jc * 512 + q];
    __syncthreads();
    int i = ib * 256 + t;
    float ui = u[i];
    float p0 = 1.f, p1 = 1.f, p2 = 1.f, p3 = 1.f;
    int c0 = 0, c1 = 0, c2 = 0, c3 = 0;
    int jbase = jc * 512;
    for (int q = 0; q < 512; q += 4) {
        float a0 = su[q], a1 = su[q + 1], a2 = su[q + 2], a3 = su[q + 3];
        int j0 = jbase + q;
        bool m0 = (a0 < ui) || (a0 == ui && j0     < i);
        bool m1 = (a1 < ui) || (a1 == ui && j0 + 1 < i);
        bool m2 = (a2 < ui) || (a2 == ui && j0 + 2 < i);
        bool m3 = (a3 < ui) || (a3 == ui && j0 + 3 < i);
        p0 *= m0 ? a0 : 1.f; c0 += m0;
        p1 *= m1 ? a1 : 1.f; c1 += m1;
        p2 *= m2 ? a2 : 1.f; c2 += m2;
        p3 *= m3 ? a3 : 1.f; c3 += m3;
    }
    apart[jc * NN + i] = (p0 * p1) * (p2 * p3);
    cpart[jc * NN + i] = (float)((c0 + c1) + (c2 + c3));
}

// ---- combine partials -> g[i], rank[i], sum(g); blocks 0,1 also reduce rv ----
__global__ __launch_bounds__(256) void k_grank(
    const float* __restrict__ u, const float* __restrict__ apart,
    const float* __restrict__ cpart, const float* __restrict__ rvp,
    float* __restrict__ g, int* __restrict__ rank,
    float* __restrict__ scal, float* __restrict__ rv_out) {
    __shared__ float sb[256];
    int i = blockIdx.x * 256 + threadIdx.x;
    float p = 1.f, c = 0.f;
    #pragma unroll
    for (int jc = 0; jc < 16; jc++) { p *= apart[jc * NN + i]; c += cpart[jc * NN + i]; }
    float gi = (1.f - u[i]) * p;
    g[i] = gi;
    rank[i] = (int)c;
    sb[threadIdx.x] = gi; __syncthreads();
    for (int s = 128; s > 0; s >>= 1) { if (threadIdx.x < s) sb[threadIdx.x] += sb[threadIdx.x + s]; __syncthreads(); }
    if (threadIdx.x == 0) atomicAdd(&scal[8], sb[0]);
    if (blockIdx.x < 2) {
        int idx = blockIdx.x * 256 + threadIdx.x;
        float acc = 0.f;
        for (int pb = 0; pb < 256; pb++) acc += rvp[pb * 512 + idx];
        rv_out[idx] = acc;
    }
}

// ---- reference's alloc_sorted[order] gather == out[rank[rank[m]]] = g[m] ----
__global__ void k_scatter(const float* __restrict__ g, const int* __restrict__ rank,
                          float* __restrict__ alloc) {
    int m = blockIdx.x * 256 + threadIdx.x;
    alloc[rank[rank[m]]] = g[m];
}

// ---- per-row epilogue: ww (inline), new_memory, usage, precedence, read_content ----
__global__ __launch_bounds__(256, 4) void k_rownew(
    const float* __restrict__ mem, const float* __restrict__ logits,
    const float* __restrict__ alloc, const float* __restrict__ u,
    const float* __restrict__ ret, const float* __restrict__ prec,
    const float* __restrict__ er, const float* __restrict__ wv,
    const float* __restrict__ rk, const float* __restrict__ rstr,
    const float* __restrict__ ag, const float* __restrict__ wg_,
    const float* __restrict__ scal,
    float* __restrict__ ww_out, float* __restrict__ nm_out,
    float* __restrict__ nu_out, float* __restrict__ np_out, float* __restrict__ rc_out)
{
    int lane = threadIdx.x & 63;
    int wave = (blockIdx.x << 2) + (threadIdx.x >> 6);
    int c = lane * 2;
    float2 er2 = *(const float2*)&er[c];
    float2 wv2 = *(const float2*)&wv[c];
    float4 rka = *(const float4*)&rk[c * 4];
    float4 rkb = *(const float4*)&rk[(c + 1) * 4];
    float4 rs4 = *(const float4*)&rstr[0];
    float n0 = rka.x * rka.x + rkb.x * rkb.x;
    float n1 = rka.y * rka.y + rkb.y * rkb.y;
    float n2 = rka.z * rka.z + rkb.z * rkb.z;
    float n3 = rka.w * rka.w + rkb.w * rkb.w;
    #pragma unroll
    for (int s = 1; s < 64; s <<= 1) {
        n0 += __shfl_xor(n0, s); n1 += __shfl_xor(n1, s);
        n2 += __shfl_xor(n2, s); n3 += __shfl_xor(n3, s);
    }
    float rkn0 = sqrtf(n0), rkn1 = sqrtf(n1), rkn2 = sqrtf(n2), rkn3 = sqrtf(n3);
    float invS = 1.f / scal[6];
    float Sg = scal[8];
    float ga = ag[0], wg = wg_[0];
    float wsum = wg * (ga * Sg + (1.f - ga));
    int i0 = wave * 4;
    for (int t = 0; t < 4; t++) {
        int i = i0 + t;
        float wwi = wg * (ga * alloc[i] + (1.f - ga) * __expf(logits[i]) * invS);
        float2 m2 = *(const float2*)&mem[i * WW_ + c];
        float nx = m2.x * (1.f - wwi * er2.x) + wwi * wv2.x;
        float ny = m2.y * (1.f - wwi * er2.y) + wwi * wv2.y;
        float2 nm2; nm2.x = nx; nm2.y = ny;
        *(float2*)&nm_out[i * WW_ + c] = nm2;
        float nq = nx * nx + ny * ny;
        float d0 = nx * rka.x + ny * rkb.x;
        float d1 = nx * rka.y + ny * rkb.y;
        float d2 = nx * rka.z + ny * rkb.z;
        float d3 = nx * rka.w + ny * rkb.w;
        #pragma unroll
        for (int s = 1; s < 64; s <<= 1) {
            nq += __shfl_xor(nq, s);
            d0 += __shfl_xor(d0, s); d1 += __shfl_xor(d1, s);
            d2 += __shfl_xor(d2, s); d3 += __shfl_xor(d3, s);
        }
        if (lane == 0) {
            float nrm = sqrtf(nq);
            float l0 = d0 / (nrm * rkn0) * rs4.x;
            float l1 = d1 / (nrm * rkn1) * rs4.y;
            float l2 = d2 / (nrm * rkn2) * rs4.z;
            float l3 = d3 / (nrm * rkn3) * rs4.w;
            float m4 = fmaxf(fmaxf(l0, l1), fmaxf(l2, l3));
            float e0 = __expf(l0 - m4), e1 = __expf(l1 - m4);
            float e2 = __expf(l2 - m4), e3 = __expf(l3 - m4);
            float si = 1.f / (e0 + e1 + e2 + e3);
            float4 rc; rc.x = e0 * si; rc.y = e1 * si; rc.z = e2 * si; rc.w = e3 * si;
            *(float4*)&rc_out[i * 4] = rc;
            ww_out[i] = wwi;
            float ui = u[i];
            nu_out[i] = (ui + wwi - ui * wwi) * ret[i];
            np_out[i] = (1.f - wsum) * prec[i] + wwi;
        }
    }
}

// ==== k_link3: no dependent DS chain in the loop; 4 blocks/CU; chunked LDS bwd reduce ====
// grid (16, 64): block = 512 cols x 128 rows. Wave w: colhalf ch=w&1 (256 cols), rowhalf rh=w>>1 (64 rows).
__global__ __launch_bounds__(256, 4) void k_link3(
    const float* __restrict__ link, const float* __restrict__ ww,
    const float* __restrict__ prec, const float* __restrict__ rw,
    float* __restrict__ nl_out, float* __restrict__ fwdp, float* __restrict__ bwdp)
{
    __shared__ float4 bbuf[16][128];   // 32 KB: [rh*8+tc][ch*64+lane]
    __shared__ float4 pbuf[16][8];     // 2 KB stage-1 partials
    const int lane = threadIdx.x & 63;
    const int w = threadIdx.x >> 6;
    const int ch = w & 1;
    const int rh = w >> 1;
    const int cb = blockIdx.x;         // 0..15
    const int rb = blockIdx.y;         // 0..63
    const int col = cb * 512 + ch * 256 + lane * 4;
    const int irow = rb * 128 + rh * 64;

    const float4 wwj = *(const float4*)&ww[col];
    const float4 pj  = *(const float4*)&prec[col];
    const float4 rj0 = *(const float4*)&rw[(col + 0) * 4];
    const float4 rj1 = *(const float4*)&rw[(col + 1) * 4];
    const float4 rj2 = *(const float4*)&rw[(col + 2) * 4];
    const float4 rj3 = *(const float4*)&rw[(col + 3) * 4];
    float4 rwT0, rwT1, rwT2, rwT3;     // rwT[r][c] = rw[col_c][r]
    rwT0.x = rj0.x; rwT0.y = rj1.x; rwT0.z = rj2.x; rwT0.w = rj3.x;
    rwT1.x = rj0.y; rwT1.y = rj1.y; rwT1.z = rj2.y; rwT1.w = rj3.y;
    rwT2.x = rj0.z; rwT2.y = rj1.z; rwT2.z = rj2.z; rwT2.w = rj3.z;
    rwT3.x = rj0.w; rwT3.y = rj1.w; rwT3.z = rj2.w; rwT3.w = rj3.w;

    float4 acc0, acc1, acc2, acc3;     // fwd acc per owned col, components = r
    acc0.x = acc0.y = acc0.z = acc0.w = 0.f;
    acc1 = acc0; acc2 = acc0; acc3 = acc0;

    size_t off = (size_t)irow * NN + col;
    float4 La = *(const float4*)&link[off];
    float4 Lb = *(const float4*)&link[off + NN];
    float wwa = ww[irow], wwb = ww[irow + 1];
    float4 rwa = *(const float4*)&rw[irow * 4];
    float4 rwb = *(const float4*)&rw[(irow + 1) * 4];

    for (int t = 0; t < 64; ++t) {
        const float4 Lcur = La; La = Lb;
        const float wwi = wwa; wwa = wwb;
        const float4 rwi = rwa; rwa = rwb;
        if (t < 62) {
            const int i2 = irow + t + 2;
            Lb  = *(const float4*)&link[off + 2 * (size_t)NN];
            wwb = ww[i2];
            rwb = *(const float4*)&rw[i2 * 4];
        }
        const float cc = 1.f - wwi;
        float4 e;
        e.x = (cc - wwj.x) * Lcur.x + wwi * pj.x;
        e.y = (cc - wwj.y) * Lcur.y + wwi * pj.y;
        e.z = (cc - wwj.z) * Lcur.z + wwi * pj.z;
        e.w = (cc - wwj.w) * Lcur.w + wwi * pj.w;
        vfloat4 ev; ev.x = e.x; ev.y = e.y; ev.z = e.z; ev.w = e.w;
        __builtin_nontemporal_store(ev, (vfloat4*)&nl_out[off]);
        off += NN;
        // fwd (register-stationary)
        acc0.x += e.x * rwi.x; acc0.y += e.x * rwi.y; acc0.z += e.x * rwi.z; acc0.w += e.x * rwi.w;
        acc1.x += e.y * rwi.x; acc1.y += e.y * rwi.y; acc1.z += e.y * rwi.z; acc1.w += e.y * rwi.w;
        acc2.x += e.z * rwi.x; acc2.y += e.z * rwi.y; acc2.z += e.z * rwi.z; acc2.w += e.z * rwi.w;
        acc3.x += e.w * rwi.x; acc3.y += e.w * rwi.y; acc3.z += e.w * rwi.z; acc3.w += e.w * rwi.w;
        // bwd partial over this lane's 4 cols: ONE independent LDS write, no shuffles
        float4 b;
        b.x = e.x * rwT0.x + e.y * rwT0.y + e.z * rwT0.z + e.w * rwT0.w;
        b.y = e.x * rwT1.x + e.y * rwT1.y + e.z * rwT1.z + e.w * rwT1.w;
        b.z = e.x * rwT2.x + e.y * rwT2.y + e.z * rwT2.z + e.w * rwT2.w;
        b.w = e.x * rwT3.x + e.y * rwT3.y + e.z * rwT3.z + e.w * rwT3.w;
        const int tc = t & 7;
        bbuf[rh * 8 + tc][ch * 64 + lane] = b;
        if (tc == 7) {
            const int chunk = t >> 3;
            __syncthreads();
            // stage 1: 128 threads, each sums 16 of 128 lane-partials for one of 16 rows
            if (threadIdx.x < 128) {
                const int rr = threadIdx.x >> 3, seg = threadIdx.x & 7;
                float4 a; a.x = a.y = a.z = a.w = 0.f;
                #pragma unroll
                for (int k = 0; k < 16; ++k) {
                    const float4 p = bbuf[rr][seg * 16 + k];
                    a.x += p.x; a.y += p.y; a.z += p.z; a.w += p.w;
                }
                pbuf[rr][seg] = a;
            }
            __syncthreads();
            // stage 2: 16 threads finalize 16 rows (runs in wave 0; next chunk's bbuf writes are safe)
            if (threadIdx.x < 16) {
                const int rr = threadIdx.x;
                float4 a; a.x = a.y = a.z = a.w = 0.f;
                #pragma unroll
                for (int s = 0; s < 8; ++s) {
                    const float4 p = pbuf[rr][s];
                    a.x += p.x; a.y += p.y; a.z += p.z; a.w += p.w;
                }
                const int row = rb * 128 + (rr >> 3) * 64 + chunk * 8 + (rr & 7);
                *(float4*)&bwdp[(size_t)cb * (NN * 4) + row * 4] = a;
            }
        }
    }
    // fwd flush: combine row-halves via LDS (reuse bbuf), write per-rb partial
    __syncthreads();
    float4* fbuf = &bbuf[0][0];        // [4][64][4] float4 = 16 KB
    fbuf[(w * 64 + lane) * 4 + 0] = acc0;
    fbuf[(w * 64 + lane) * 4 + 1] = acc1;
    fbuf[(w * 64 + lane) * 4 + 2] = acc2;
    fbuf[(w * 64 + lane) * 4 + 3] = acc3;
    __syncthreads();
    #pragma unroll
    for (int rep = 0; rep < 2; ++rep) {
        const int lc = threadIdx.x * 2 + rep;        // 0..511 col within band
        const int ch2 = lc >> 8;
        const int ls = (lc & 255) >> 2;
        const int a = lc & 3;
        const float4 s0 = fbuf[(ch2 * 64 + ls) * 4 + a];
        const float4 s1 = fbuf[((ch2 + 2) * 64 + ls) * 4 + a];
        float4 s; s.x = s0.x + s1.x; s.y = s0.y + s1.y; s.z = s0.z + s1.z; s.w = s0.w + s1.w;
        *(float4*)&fwdp[(size_t)rb * (NN * 4) + (cb * 512 + lc) * 4] = s;
    }
}

// ---- reduce partials + combine into new read weightings (8 waves/CU, coalesced) ----
__global__ __launch_bounds__(256) void k_final3(
    const float* __restrict__ fwdp, const float* __restrict__ bwdp,
    const float* __restrict__ rc, const float* __restrict__ modes,
    float* __restrict__ out) {
    __shared__ float fs[4][64], bs[4][64];
    const int lane = threadIdx.x & 63;
    const int w = threadIdx.x >> 6;
    const int o = blockIdx.x * 64 + lane;    // grid 512 -> 32768
    float f = 0.f;
    #pragma unroll
    for (int k = 0; k < 16; ++k) f += fwdp[(size_t)(w * 16 + k) * (NN * 4) + o];
    float b = 0.f;
    #pragma unroll
    for (int k = 0; k < 4; ++k) b += bwdp[(size_t)(w * 4 + k) * (NN * 4) + o];
    fs[w][lane] = f; bs[w][lane] = b;
    __syncthreads();
    if (threadIdx.x < 64) {
        const float F = fs[0][lane] + fs[1][lane] + fs[2][lane] + fs[3][lane];
        const float B = bs[0][lane] + bs[1][lane] + bs[2][lane] + bs[3][lane];
        const int r = o & 3;
        out[o] = B * modes[r * 3] + rc[o] * modes[r * 3 + 1] + F * modes[r * 3 + 2];
    }
}

// ==== fallback (round-4, proven) k_link + k_final ====
__global__ __launch_bounds__(256, 4) void k_link(
    const float* __restrict__ link, const float* __restrict__ ww,
    const float* __restrict__ prec, const float* __restrict__ rw,
    float* __restrict__ nl_out, float* __restrict__ fwd, float* __restrict__ bwd)
{
    __shared__ float part[64][16][4];
    __shared__ float fl[4][256][4];
    const int lane = threadIdx.x & 63;
    const int w = threadIdx.x >> 6;
    const int j = blockIdx.x * 256 + lane * 4;
    const float4 wwj = *(const float4*)&ww[j];
    const float4 pj  = *(const float4*)&prec[j];
    const float4 rwj0 = *(const float4*)&rw[j * 4];
    const float4 rwj1 = *(const float4*)&rw[j * 4 + 4];
    const float4 rwj2 = *(const float4*)&rw[j * 4 + 8];
    const float4 rwj3 = *(const float4*)&rw[j * 4 + 12];
    float fa[4][4];
    #pragma unroll
    for (int a = 0; a < 4; a++)
        #pragma unroll
        for (int r = 0; r < 4; r++) fa[a][r] = 0.f;
    for (int sub = 0; sub < 4; ++sub) {
        const int i00 = blockIdx.y * 256 + sub * 64;
        const int irow0 = i00 + w * 16;
        #pragma unroll 4
        for (int t = 0; t < 16; ++t) {
            const int i = irow0 + t;
            const float wwi = ww[i];
            const float4 rwi = *(const float4*)&rw[i * 4];
            const size_t off = (size_t)i * NN + j;
            const float4 Lv = *(const float4*)&link[off];
            const float c0 = 1.f - wwi;
            float4 e;
            e.x = (c0 - wwj.x) * Lv.x + wwi * pj.x;
            e.y = (c0 - wwj.y) * Lv.y + wwi * pj.y;
            e.z = (c0 - wwj.z) * Lv.z + wwi * pj.z;
            e.w = (c0 - wwj.w) * Lv.w + wwi * pj.w;
            vfloat4 ev; ev.x = e.x; ev.y = e.y; ev.z = e.z; ev.w = e.w;
            __builtin_nontemporal_store(ev, (vfloat4*)&nl_out[off]);
            fa[0][0] += e.x * rwi.x; fa[0][1] += e.x * rwi.y; fa[0][2] += e.x * rwi.z; fa[0][3] += e.x * rwi.w;
            fa[1][0] += e.y * rwi.x; fa[1][1] += e.y * rwi.y; fa[1][2] += e.y * rwi.z; fa[1][3] += e.y * rwi.w;
            fa[2][0] += e.z * rwi.x; fa[2][1] += e.z * rwi.y; fa[2][2] += e.z * rwi.z; fa[2][3] += e.z * rwi.w;
            fa[3][0] += e.w * rwi.x; fa[3][1] += e.w * rwi.y; fa[3][2] += e.w * rwi.z; fa[3][3] += e.w * rwi.w;
            float b0 = e.x * rwj0.x + e.y * rwj1.x + e.z * rwj2.x + e.w * rwj3.x;
            float b1 = e.x * rwj0.y + e.y * rwj1.y + e.z * rwj2.y + e.w * rwj3.y;
            float b2 = e.x * rwj0.z + e.y * rwj1.z + e.z * rwj2.z + e.w * rwj3.z;
            float b3 = e.x * rwj0.w + e.y * rwj1.w + e.z * rwj2.w + e.w * rwj3.w;
            float u01 = (lane & 1) ? b0 : b1;
            float v01 = __shfl_xor(u01, 1);
            float A = ((lane & 1) ? b1 : b0) + v01;
            float u23 = (lane & 1) ? b2 : b3;
            float v23 = __shfl_xor(u23, 1);
            float B = ((lane & 1) ? b3 : b2) + v23;
            float uu = (lane & 2) ? A : B;
            float vv = __shfl_xor(uu, 2);
            float S = ((lane & 2) ? B : A) + vv;
            #pragma unroll
            for (int s = 4; s < 64; s <<= 1) S += __shfl_xor(S, s);
            const int row = w * 16 + t;
            if (lane < 4) part[row][((lane >> 2) + row) & 15][lane & 3] = S;
        }
        __syncthreads();
        if (threadIdx.x < 64) {
            const int row = threadIdx.x;
            float4 acc; acc.x = 0.f; acc.y = 0.f; acc.z = 0.f; acc.w = 0.f;
            #pragma unroll
            for (int k = 0; k < 16; ++k) {
                const float4 p = *(const float4*)&part[row][(k + row) & 15][0];
                acc.x += p.x; acc.y += p.y; acc.z += p.z; acc.w += p.w;
            }
            const int i = i00 + row;
            atomicAdd(&bwd[i * 4 + 0], acc.x);
            atomicAdd(&bwd[i * 4 + 1], acc.y);
            atomicAdd(&bwd[i * 4 + 2], acc.z);
            atomicAdd(&bwd[i * 4 + 3], acc.w);
        }
        __syncthreads();
    }
    #pragma unroll
    for (int a = 0; a < 4; a++)
        #pragma unroll
        for (int r = 0; r < 4; r++)
            fl[w][lane * 4 + a][r] = fa[a][r];
    __syncthreads();
    const int col = threadIdx.x;
    const float4 s0 = *(const float4*)&fl[0][col][0];
    const float4 s1 = *(const float4*)&fl[1][col][0];
    const float4 s2 = *(const float4*)&fl[2][col][0];
    const float4 s3 = *(const float4*)&fl[3][col][0];
    atomicAdd(&fwd[(blockIdx.x * 256 + col) * 4 + 0], s0.x + s1.x + s2.x + s3.x);
    atomicAdd(&fwd[(blockIdx.x * 256 + col) * 4 + 1], s0.y + s1.y + s2.y + s3.y);
    atomicAdd(&fwd[(blockIdx.x * 256 + col) * 4 + 2], s0.z + s1.z + s2.z + s3.z);
    atomicAdd(&fwd[(blockIdx.x * 256 + col) * 4 + 3], s0.w + s1.w + s2.w + s3.w);
}

__global__ void k_final(const float* __restrict__ fwd, const float* __restrict__ bwd,
                        const float* __restrict__ rc, const float* __restrict__ modes,
                        float* __restrict__ out) {
    int idx = blockIdx.x * 256 + threadIdx.x;
    int r = idx & 3;
    float m0 = modes[r * 3], m1 = modes[r * 3 + 1], m2 = modes[r * 3 + 2];
    out[idx] = bwd[idx] * m0 + rc[idx] * m1 + fwd[idx] * m2;
}

extern "C" void kernel_launch(void* const* d_in, const int* in_sizes, int n_in,
                              void* d_out, int out_size, void* d_ws, size_t ws_size,
                              hipStream_t stream) {
    const float* mem   = (const float*)d_in[0];
    const float* u     = (const float*)d_in[1];
    const float* prec  = (const float*)d_in[2];
    const float* link  = (const float*)d_in[3];
    const float* rw    = (const float*)d_in[4];
    const float* rk    = (const float*)d_in[5];
    const float* rstr  = (const float*)d_in[6];
    const float* wk    = (const float*)d_in[7];
    const float* wstr  = (const float*)d_in[8];
    const float* er    = (const float*)d_in[9];
    const float* wv    = (const float*)d_in[10];
    const float* fg    = (const float*)d_in[11];
    const float* ag    = (const float*)d_in[12];
    const float* wg    = (const float*)d_in[13];
    const float* modes = (const float*)d_in[14];
    float* out = (float*)d_out;
    float* ws  = (float*)d_ws;
    float* nlr = out + O_NL;

    (void)hipMemsetAsync(ws + S_SCAL, 0, 32 * sizeof(float), stream);

    k_rowstats<<<256, 256, 0, stream>>>(mem, rw, wk, fg, wstr,
                                        nlr + P_RVP, ws + S_LOGITS, ws + S_RET, ws + S_SCAL);
    k_apart<<<512, 256, 0, stream>>>(u, nlr + P_APART, nlr + P_CPART, ws + S_FWD);
    k_grank<<<32, 256, 0, stream>>>(u, nlr + P_APART, nlr + P_CPART, nlr + P_RVP,
                                    ws + S_G, (int*)(ws + S_RANK), ws + S_SCAL, out + O_RV);
    k_scatter<<<32, 256, 0, stream>>>(ws + S_G, (const int*)(ws + S_RANK), ws + S_ALLOC);
    k_rownew<<<512, 256, 0, stream>>>(mem, ws + S_LOGITS, ws + S_ALLOC, u, ws + S_RET,
                                      prec, er, wv, rk, rstr, ag, wg, ws + S_SCAL,
                                      ws + S_WW, out + O_NM, out + O_NU, out + O_NP, ws + S_RC);

    if (ws_size >= WS_NEED_BYTES) {
        dim3 lg(16, 64);
        k_link3<<<lg, 256, 0, stream>>>(link, ws + S_WW, prec, rw, out + O_NL,
                                        ws + S_FWDP, ws + S_BWDP);
        k_final3<<<512, 256, 0, stream>>>(ws + S_FWDP, ws + S_BWDP, ws + S_RC, modes, out + O_NR);
    } else {
        dim3 lg(32, 32);
        k_link<<<lg, 256, 0, stream>>>(link, ws + S_WW, prec, rw, out + O_NL,
                                       ws + S_FWD, ws + S_BWD);
        k_final<<<128, 256, 0, stream>>>(ws + S_FWD, ws + S_BWD, ws + S_RC, modes, out + O_NR);
    }
}